// Round 1
// baseline (1049.395 us; speedup 1.0000x reference)
//
#include <hip/hip_runtime.h>
#include <math.h>

#define B_ 8
#define S_ 1024
#define E_ 768
#define H_ 12
#define P_ 64

// ---------------------------------------------------------------------------
// Common 64x64 output tile fp32 GEMM core: 256 threads, 4x4 acc per thread,
// BK=16. A is row-major (lda), B is row-major (ldb). A points at the tile's
// first row (m0 applied by caller); Bm points at col n0 of B (n offset
// applied by caller). K must be a multiple of 16.
// ---------------------------------------------------------------------------
__device__ __forceinline__ void gemm64_core(const float* __restrict__ A, int lda,
                                            const float* __restrict__ Bm, int ldb,
                                            int K, float (&acc)[4][4],
                                            float (*As)[64], float (*Bs)[64])
{
    const int tid = threadIdx.x;
    const int tx = tid & 15, ty = tid >> 4;
    const int ar  = tid >> 2;  // 0..63: A-tile row this thread loads
    const int akv = tid & 3;   // which float4 along K
    const int bkr = tid >> 4;  // 0..15: B-tile k-row this thread loads
    const int bnv = tid & 15;  // which float4 along N

    for (int k0 = 0; k0 < K; k0 += 16) {
        __syncthreads();
        float4 av = *(const float4*)(A + (size_t)ar * lda + k0 + 4 * akv);
        As[4 * akv + 0][ar] = av.x;
        As[4 * akv + 1][ar] = av.y;
        As[4 * akv + 2][ar] = av.z;
        As[4 * akv + 3][ar] = av.w;
        *(float4*)&Bs[bkr][4 * bnv] =
            *(const float4*)(Bm + (size_t)(k0 + bkr) * ldb + 4 * bnv);
        __syncthreads();
#pragma unroll
        for (int kk = 0; kk < 16; ++kk) {
            float4 a4 = *(const float4*)&As[kk][4 * ty];
            float4 b4 = *(const float4*)&Bs[kk][4 * tx];
            float aa[4] = {a4.x, a4.y, a4.z, a4.w};
            float bb[4] = {b4.x, b4.y, b4.z, b4.w};
#pragma unroll
            for (int i = 0; i < 4; ++i)
#pragma unroll
                for (int j = 0; j < 4; ++j)
                    acc[i][j] += aa[i] * bb[j];
        }
    }
}

// ---------------------------------------------------------------------------
// Stage 1: k[b,h,s,p] = sum_e x[b,s,e] * key_proj[h,e,p]   (z=0)
//          v[b,h,s,p] = sum_e x[b,s,e] * value_proj[h,e,p] (z=1)
// grid (M/64=128, H=12, 2)
// ---------------------------------------------------------------------------
__global__ __launch_bounds__(256) void proj_kv_kernel(
    const float* __restrict__ x,
    const float* __restrict__ kproj,
    const float* __restrict__ vproj,
    float* __restrict__ kbuf,
    float* __restrict__ vbuf)
{
    __shared__ float As[16][64];
    __shared__ float Bs[16][64];
    const int tid = threadIdx.x;
    const int tx = tid & 15, ty = tid >> 4;
    const int m0 = blockIdx.x * 64;
    const int h  = blockIdx.y;
    const int z  = blockIdx.z;
    const float* W = (z ? vproj : kproj) + (size_t)h * E_ * P_;
    float* outb = z ? vbuf : kbuf;

    float acc[4][4] = {};
    gemm64_core(x + (size_t)m0 * E_, E_, W, P_, E_, acc, As, Bs);

    const int b  = m0 / S_;
    const int s0 = m0 - b * S_;
    float* cbase = outb + ((size_t)(b * H_ + h) * S_ + s0) * P_;
#pragma unroll
    for (int i = 0; i < 4; ++i) {
        float4 val = make_float4(acc[i][0], acc[i][1], acc[i][2], acc[i][3]);
        *(float4*)(cbase + (size_t)(4 * ty + i) * P_ + 4 * tx) = val;
    }
}

// ---------------------------------------------------------------------------
// Stage 2: qv[b,h] = q_heads[h] (S x S) @ v[b,h] (S x P)
// grid (S/64=16, B*H=96)
// ---------------------------------------------------------------------------
__global__ __launch_bounds__(256) void qv_kernel(
    const float* __restrict__ qheads,
    const float* __restrict__ vbuf,
    float* __restrict__ qvbuf)
{
    __shared__ float As[16][64];
    __shared__ float Bs[16][64];
    const int tid = threadIdx.x;
    const int tx = tid & 15, ty = tid >> 4;
    const int i0 = blockIdx.x * 64;
    const int bh = blockIdx.y;
    const int h  = bh % H_;

    const float* A  = qheads + (size_t)h * S_ * S_ + (size_t)i0 * S_;
    const float* Bm = vbuf + (size_t)bh * S_ * P_;
    float* C        = qvbuf + (size_t)bh * S_ * P_ + (size_t)i0 * P_;

    float acc[4][4] = {};
    gemm64_core(A, S_, Bm, P_, S_, acc, As, Bs);

#pragma unroll
    for (int i = 0; i < 4; ++i) {
        float4 val = make_float4(acc[i][0], acc[i][1], acc[i][2], acc[i][3]);
        *(float4*)(C + (size_t)(4 * ty + i) * P_ + 4 * tx) = val;
    }
}

// ---------------------------------------------------------------------------
// Stage 3: flash attention. Queries = k rows, Keys = qv rows, Values = v,
// causal mask j<=i, scale 1/sqrt(E). Output attn2[b, s, h*P + p].
// grid (S/64=16, B*H=96), 256 threads.
// ---------------------------------------------------------------------------
__global__ __launch_bounds__(256) void flash_kernel(
    const float* __restrict__ kbuf,
    const float* __restrict__ qvbuf,
    const float* __restrict__ vbuf,
    float* __restrict__ attn2)
{
    __shared__ float Qs[64][68];
    __shared__ float KPs[64][68];  // K tile during QK^T; reused as P tile for PV
    __shared__ float Vs[64][68];

    const int tid = threadIdx.x;
    const int tx = tid & 15, ty = tid >> 4;
    const int qb = blockIdx.x;
    const int bh = blockIdx.y;
    const int b = bh / H_, h = bh % H_;

    const float* Q  = kbuf  + (size_t)bh * S_ * P_;
    const float* Kp = qvbuf + (size_t)bh * S_ * P_;
    const float* V  = vbuf  + (size_t)bh * S_ * P_;

    // load Q tile once (rows qb*64 .. qb*64+63, all 64 P cols)
#pragma unroll
    for (int rep = 0; rep < 4; ++rep) {
        int idx = rep * 256 + tid;
        int r = idx >> 4, c4 = idx & 15;
        *(float4*)&Qs[r][4 * c4] =
            *(const float4*)(Q + (size_t)(qb * 64 + r) * P_ + 4 * c4);
    }

    float o[4][4] = {};
    float mrow[4], lrow[4];
#pragma unroll
    for (int i = 0; i < 4; ++i) { mrow[i] = -1e30f; lrow[i] = 0.f; }

    const float scale = 0.03608439182435161f; // 1/sqrt(768)

    for (int jt = 0; jt <= qb; ++jt) {
        __syncthreads();  // previous iter's KPs/Vs reads done (also fences Qs stores, iter 0)
#pragma unroll
        for (int rep = 0; rep < 4; ++rep) {
            int idx = rep * 256 + tid;
            int r = idx >> 4, c4 = idx & 15;
            *(float4*)&KPs[r][4 * c4] =
                *(const float4*)(Kp + (size_t)(jt * 64 + r) * P_ + 4 * c4);
            *(float4*)&Vs[r][4 * c4] =
                *(const float4*)(V + (size_t)(jt * 64 + r) * P_ + 4 * c4);
        }
        __syncthreads();

        // s = Q @ K^T (rows 4ty+i, cols 4tx+j), dot over P=64
        float s[4][4] = {};
#pragma unroll 4
        for (int p4 = 0; p4 < 16; ++p4) {
            float4 q[4], kf[4];
#pragma unroll
            for (int i = 0; i < 4; ++i) q[i]  = *(const float4*)&Qs[4 * ty + i][4 * p4];
#pragma unroll
            for (int j = 0; j < 4; ++j) kf[j] = *(const float4*)&KPs[4 * tx + j][4 * p4];
#pragma unroll
            for (int i = 0; i < 4; ++i)
#pragma unroll
                for (int j = 0; j < 4; ++j)
                    s[i][j] += q[i].x * kf[j].x + q[i].y * kf[j].y +
                               q[i].z * kf[j].z + q[i].w * kf[j].w;
        }

        const bool diag = (jt == qb);
#pragma unroll
        for (int i = 0; i < 4; ++i) {
            int gi = qb * 64 + 4 * ty + i;
#pragma unroll
            for (int j = 0; j < 4; ++j) {
                int gj = jt * 64 + 4 * tx + j;
                float val = s[i][j] * scale;
                if (diag && gj > gi) val = -1e30f;
                s[i][j] = val;
            }
        }

        __syncthreads();  // everyone done reading KPs; reuse it for P

        // online softmax per row (row = 16 lanes sharing ty)
#pragma unroll
        for (int i = 0; i < 4; ++i) {
            float rmax = fmaxf(fmaxf(s[i][0], s[i][1]), fmaxf(s[i][2], s[i][3]));
#pragma unroll
            for (int off = 1; off < 16; off <<= 1)
                rmax = fmaxf(rmax, __shfl_xor(rmax, off, 16));
            float mnew  = fmaxf(mrow[i], rmax);
            float alpha = __expf(mrow[i] - mnew);
            float rs = 0.f;
#pragma unroll
            for (int j = 0; j < 4; ++j) {
                float p = __expf(s[i][j] - mnew);
                s[i][j] = p;
                rs += p;
            }
#pragma unroll
            for (int off = 1; off < 16; off <<= 1)
                rs += __shfl_xor(rs, off, 16);
            lrow[i] = lrow[i] * alpha + rs;
            mrow[i] = mnew;
#pragma unroll
            for (int j = 0; j < 4; ++j) o[i][j] *= alpha;
            *(float4*)&KPs[4 * ty + i][4 * tx] =
                make_float4(s[i][0], s[i][1], s[i][2], s[i][3]);
        }
        __syncthreads();

        // o += P @ V  (o rows 4ty+i, cols 4tx+j; sum over 64 j's)
#pragma unroll 4
        for (int j4 = 0; j4 < 16; ++j4) {
            float4 pr[4], vv[4];
#pragma unroll
            for (int i = 0; i < 4; ++i)  pr[i]  = *(const float4*)&KPs[4 * ty + i][4 * j4];
#pragma unroll
            for (int jj = 0; jj < 4; ++jj) vv[jj] = *(const float4*)&Vs[4 * j4 + jj][4 * tx];
#pragma unroll
            for (int i = 0; i < 4; ++i) {
                float pv[4] = {pr[i].x, pr[i].y, pr[i].z, pr[i].w};
#pragma unroll
                for (int jj = 0; jj < 4; ++jj) {
                    o[i][0] += pv[jj] * vv[jj].x;
                    o[i][1] += pv[jj] * vv[jj].y;
                    o[i][2] += pv[jj] * vv[jj].z;
                    o[i][3] += pv[jj] * vv[jj].w;
                }
            }
        }
    }

    // epilogue: attn2[b, i, h*64 + p] = o / l
#pragma unroll
    for (int i = 0; i < 4; ++i) {
        int gi = qb * 64 + 4 * ty + i;
        float inv = 1.0f / lrow[i];
        float4 val = make_float4(o[i][0] * inv, o[i][1] * inv,
                                 o[i][2] * inv, o[i][3] * inv);
        *(float4*)(attn2 + ((size_t)b * S_ + gi) * (H_ * P_) + h * P_ + 4 * tx) = val;
    }
}

// ---------------------------------------------------------------------------
// Stage 4: out (8192 x 768) = attn2 (8192 x 768) @ lifting (768 x 768)
// grid (128, 12)
// ---------------------------------------------------------------------------
__global__ __launch_bounds__(256) void lift_kernel(
    const float* __restrict__ attn2,
    const float* __restrict__ lifting,
    float* __restrict__ outp)
{
    __shared__ float As[16][64];
    __shared__ float Bs[16][64];
    const int tid = threadIdx.x;
    const int tx = tid & 15, ty = tid >> 4;
    const int m0 = blockIdx.x * 64;
    const int n0 = blockIdx.y * 64;

    float acc[4][4] = {};
    gemm64_core(attn2 + (size_t)m0 * (H_ * P_), H_ * P_, lifting + n0, E_,
                H_ * P_, acc, As, Bs);

    float* C = outp + (size_t)m0 * E_ + n0;
#pragma unroll
    for (int i = 0; i < 4; ++i) {
        float4 val = make_float4(acc[i][0], acc[i][1], acc[i][2], acc[i][3]);
        *(float4*)(C + (size_t)(4 * ty + i) * E_ + 4 * tx) = val;
    }
}

extern "C" void kernel_launch(void* const* d_in, const int* in_sizes, int n_in,
                              void* d_out, int out_size, void* d_ws, size_t ws_size,
                              hipStream_t stream) {
    const float* x       = (const float*)d_in[0];
    const float* kproj   = (const float*)d_in[1];
    const float* vproj   = (const float*)d_in[2];
    const float* qheads  = (const float*)d_in[3];
    const float* lifting = (const float*)d_in[4];
    float* out = (float*)d_out;
    float* ws  = (float*)d_ws;

    const size_t NBHSP = (size_t)B_ * H_ * S_ * P_;  // 6,291,456
    float* kbuf  = ws;
    float* vbuf  = ws + NBHSP;
    float* qvbuf = ws + 2 * NBHSP;
    float* attn2 = ws + 3 * NBHSP;

    proj_kv_kernel<<<dim3((B_ * S_) / 64, H_, 2), 256, 0, stream>>>(
        x, kproj, vproj, kbuf, vbuf);
    qv_kernel<<<dim3(S_ / 64, B_ * H_), 256, 0, stream>>>(qheads, vbuf, qvbuf);
    flash_kernel<<<dim3(S_ / 64, B_ * H_), 256, 0, stream>>>(kbuf, qvbuf, vbuf, attn2);
    lift_kernel<<<dim3((B_ * S_) / 64, E_ / 64), 256, 0, stream>>>(attn2, lifting, out);
}

// Round 2
// 357.956 us; speedup vs baseline: 2.9316x; 2.9316x over previous
//
#include <hip/hip_runtime.h>
#include <math.h>

#define B_ 8
#define S_ 1024
#define E_ 768
#define H_ 12
#define P_ 64

typedef __attribute__((ext_vector_type(8))) short bf16x8;
typedef __attribute__((ext_vector_type(4))) float f32x4;

__device__ __forceinline__ short f2bf(float f) {
    union { float f; unsigned u; } v; v.f = f;
    unsigned r = v.u + 0x7FFFu + ((v.u >> 16) & 1u);  // round-to-nearest-even
    return (short)(r >> 16);
}

// ---------------------------------------------------------------------------
// fp32 -> bf16 straight conversion (n multiple of 1024)
// ---------------------------------------------------------------------------
__global__ __launch_bounds__(256) void conv_bf16_kernel(
    const float4* __restrict__ src, ushort4* __restrict__ dst)
{
    int idx = blockIdx.x * 256 + threadIdx.x;
    float4 f = src[idx];
    ushort4 u;
    u.x = (unsigned short)f2bf(f.x);
    u.y = (unsigned short)f2bf(f.y);
    u.z = (unsigned short)f2bf(f.z);
    u.w = (unsigned short)f2bf(f.w);
    dst[idx] = u;
}

// ---------------------------------------------------------------------------
// fp32 [batch][R][C] -> bf16 [batch][C][R] transpose. grid (R/64, C/64, batch)
// ---------------------------------------------------------------------------
__global__ __launch_bounds__(256) void conv_T_kernel(
    const float* __restrict__ src0, short* __restrict__ dst0, int R, int C)
{
    __shared__ short T[64][72];
    const int t = threadIdx.x;
    const int r0 = blockIdx.x * 64, c0 = blockIdx.y * 64;
    const size_t bo = (size_t)blockIdx.z * R * C;
    const float* src = src0 + bo;
    short* dst = dst0 + bo;
#pragma unroll
    for (int i = 0; i < 4; ++i) {
        int id = i * 256 + t;
        int r = id >> 4, c4 = id & 15;
        float4 f = *(const float4*)(src + (size_t)(r0 + r) * C + c0 + c4 * 4);
        T[c4 * 4 + 0][r] = f2bf(f.x);
        T[c4 * 4 + 1][r] = f2bf(f.y);
        T[c4 * 4 + 2][r] = f2bf(f.z);
        T[c4 * 4 + 3][r] = f2bf(f.w);
    }
    __syncthreads();
#pragma unroll
    for (int i = 0; i < 2; ++i) {
        int id = i * 256 + t;
        int cc = id >> 3, r8 = id & 7;
        *(uint4*)(dst + (size_t)(c0 + cc) * R + r0 + r8 * 8) = *(const uint4*)&T[cc][r8 * 8];
    }
}

// ---------------------------------------------------------------------------
// MFMA GEMM core: C(128x64) = A(128xK) @ Bt(64xK)^T.
// A row-major bf16 (lda), Bt row-major bf16 (ldb, rows = output cols).
// 256 threads = 4 waves; wave w does rows [32w, 32w+32): acc[2][4] frags.
// K multiple of 64. LDS rows padded to 72 shorts (stride 4 dwords mod 32:
// 2-way bank aliasing only = free).
// Fragment maps (verified m89/m120): A[m=lane&15][k=quad*8+j],
// Bt[n=lane&15][k=quad*8+j], D[row=quad*4+reg][col=lane&15].
// ---------------------------------------------------------------------------
__device__ __forceinline__ void mfma_gemm_128x64(
    const short* __restrict__ A, int lda,
    const short* __restrict__ Bt, int ldb, int K,
    short (*As)[72], short (*Bs)[72], f32x4 (&acc)[2][4])
{
    const int tid = threadIdx.x;
    const int w = tid >> 6, lane = tid & 63, quad = lane >> 4, ln = lane & 15;

    for (int k0 = 0; k0 < K; k0 += 64) {
        __syncthreads();
#pragma unroll
        for (int i = 0; i < 4; ++i) {           // A tile: 128 rows x 8 chunks
            int id = i * 256 + tid;
            int r = id >> 3, c8 = id & 7;
            *(uint4*)&As[r][c8 * 8] = *(const uint4*)(A + (size_t)r * lda + k0 + c8 * 8);
        }
#pragma unroll
        for (int i = 0; i < 2; ++i) {           // Bt tile: 64 rows x 8 chunks
            int id = i * 256 + tid;
            int r = id >> 3, c8 = id & 7;
            *(uint4*)&Bs[r][c8 * 8] = *(const uint4*)(Bt + (size_t)r * ldb + k0 + c8 * 8);
        }
        __syncthreads();
#pragma unroll
        for (int kc = 0; kc < 2; ++kc) {
            bf16x8 a0 = *(const bf16x8*)&As[w * 32 + ln][kc * 32 + quad * 8];
            bf16x8 a1 = *(const bf16x8*)&As[w * 32 + 16 + ln][kc * 32 + quad * 8];
#pragma unroll
            for (int ni = 0; ni < 4; ++ni) {
                bf16x8 b = *(const bf16x8*)&Bs[ni * 16 + ln][kc * 32 + quad * 8];
                acc[0][ni] = __builtin_amdgcn_mfma_f32_16x16x32_bf16(a0, b, acc[0][ni], 0, 0, 0);
                acc[1][ni] = __builtin_amdgcn_mfma_f32_16x16x32_bf16(a1, b, acc[1][ni], 0, 0, 0);
            }
        }
    }
}

// ---------------------------------------------------------------------------
// Stage 1: k = x @ key_proj (z=0, row-major out), v = x @ value_proj
// (z=1, TRANSPOSED out vT[b,h,p,s]). grid (64, H, 2).
// ---------------------------------------------------------------------------
__global__ __launch_bounds__(256) void proj_kv_mfma(
    const short* __restrict__ xb,
    const short* __restrict__ kTw,   // [h][p][e] bf16
    const short* __restrict__ vTw,
    short* __restrict__ kb,          // [b][h][s][p]
    short* __restrict__ vTb)         // [b][h][p][s]
{
    __shared__ short As[128][72];
    __shared__ short Bs[64][72];
    const int tid = threadIdx.x;
    const int w = tid >> 6, lane = tid & 63, quad = lane >> 4, ln = lane & 15;
    const int m0 = blockIdx.x * 128;
    const int h = blockIdx.y, z = blockIdx.z;

    const short* Bt = (z ? vTw : kTw) + (size_t)h * P_ * E_;
    f32x4 acc[2][4] = {};
    mfma_gemm_128x64(xb + (size_t)m0 * E_, E_, Bt, E_, E_, As, Bs, acc);

    const int b = m0 >> 10;
    const int sbase = (m0 & 1023) + w * 32;
    if (z == 0) {
        short* outp = kb + ((size_t)(b * H_ + h)) * S_ * P_;
#pragma unroll
        for (int mi = 0; mi < 2; ++mi)
#pragma unroll
            for (int ni = 0; ni < 4; ++ni)
#pragma unroll
                for (int r = 0; r < 4; ++r) {
                    int s = sbase + mi * 16 + quad * 4 + r;
                    outp[(size_t)s * P_ + ni * 16 + ln] = f2bf(acc[mi][ni][r]);
                }
    } else {
        short* outp = vTb + ((size_t)(b * H_ + h)) * P_ * S_;
#pragma unroll
        for (int mi = 0; mi < 2; ++mi)
#pragma unroll
            for (int ni = 0; ni < 4; ++ni) {
                int p = ni * 16 + ln;
                int s = sbase + mi * 16 + quad * 4;  // 4 consecutive s in regs
                ushort4 u;
                u.x = (unsigned short)f2bf(acc[mi][ni][0]);
                u.y = (unsigned short)f2bf(acc[mi][ni][1]);
                u.z = (unsigned short)f2bf(acc[mi][ni][2]);
                u.w = (unsigned short)f2bf(acc[mi][ni][3]);
                *(ushort4*)(outp + (size_t)p * S_ + s) = u;
            }
    }
}

// ---------------------------------------------------------------------------
// Stage 2: qv[b,h] = q_heads[h] @ v[b,h]; B-operand is vT (already Bt form).
// grid (8, B*H). Output row-major bf16 [b][h][s][p].
// ---------------------------------------------------------------------------
__global__ __launch_bounds__(256) void qv_mfma(
    const short* __restrict__ qhb,
    const short* __restrict__ vTb,
    short* __restrict__ qvb)
{
    __shared__ short As[128][72];
    __shared__ short Bs[64][72];
    const int tid = threadIdx.x;
    const int w = tid >> 6, lane = tid & 63, quad = lane >> 4, ln = lane & 15;
    const int m0 = blockIdx.x * 128;
    const int bh = blockIdx.y;
    const int h = bh % H_;

    f32x4 acc[2][4] = {};
    mfma_gemm_128x64(qhb + (size_t)h * S_ * S_ + (size_t)m0 * S_, S_,
                     vTb + (size_t)bh * P_ * S_, S_, S_, As, Bs, acc);

    short* outp = qvb + (size_t)bh * S_ * P_;
#pragma unroll
    for (int mi = 0; mi < 2; ++mi)
#pragma unroll
        for (int ni = 0; ni < 4; ++ni)
#pragma unroll
            for (int r = 0; r < 4; ++r) {
                int s = m0 + w * 32 + mi * 16 + quad * 4 + r;
                outp[(size_t)s * P_ + ni * 16 + ln] = f2bf(acc[mi][ni][r]);
            }
}

// ---------------------------------------------------------------------------
// Stage 3: flash attention (Q=k rows, K=qv rows, V via vT), causal, 1/sqrt(E).
// grid (16, B*H) with grid.x reversed for load balance. Wave w owns Q rows
// [qb*64+16w, +16). P relayout via per-wave LDS region (m120 recipe).
// ---------------------------------------------------------------------------
__global__ __launch_bounds__(256) void flash_mfma(
    const short* __restrict__ kb,
    const short* __restrict__ qvb,
    const short* __restrict__ vTb,
    short* __restrict__ attn2)
{
    __shared__ short Qs[64][72];
    __shared__ short Ks[64][72];
    __shared__ short Vts[64][72];
    __shared__ short Ps[64][72];

    const int tid = threadIdx.x;
    const int w = tid >> 6, lane = tid & 63, quad = lane >> 4, ln = lane & 15;
    const int qb = (int)(gridDim.x - 1 - blockIdx.x);   // long blocks first
    const int bh = blockIdx.y;
    const int b = bh / H_, h = bh % H_;

    const short* Q  = kb  + (size_t)bh * S_ * P_ + (size_t)qb * 64 * P_;
    const short* K  = qvb + (size_t)bh * S_ * P_;
    const short* Vt = vTb + (size_t)bh * P_ * S_;

#pragma unroll
    for (int i = 0; i < 2; ++i) {
        int id = i * 256 + tid;
        int r = id >> 3, c8 = id & 7;
        *(uint4*)&Qs[r][c8 * 8] = *(const uint4*)(Q + (size_t)r * P_ + c8 * 8);
    }
    __syncthreads();
    bf16x8 qf[2];
    qf[0] = *(const bf16x8*)&Qs[w * 16 + ln][quad * 8];
    qf[1] = *(const bf16x8*)&Qs[w * 16 + ln][32 + quad * 8];

    f32x4 o[4] = {};
    float m_r[4], l_r[4];
#pragma unroll
    for (int r = 0; r < 4; ++r) { m_r[r] = -1e30f; l_r[r] = 0.f; }

    const float scale = 0.03608439182435161f;  // 1/sqrt(768)

    for (int jt = 0; jt <= qb; ++jt) {
        __syncthreads();   // prior iter's Vts/Ps reads complete
#pragma unroll
        for (int i = 0; i < 2; ++i) {
            int id = i * 256 + tid;
            int r = id >> 3, c8 = id & 7;
            *(uint4*)&Ks[r][c8 * 8]  = *(const uint4*)(K + (size_t)(jt * 64 + r) * P_ + c8 * 8);
            *(uint4*)&Vts[r][c8 * 8] = *(const uint4*)(Vt + (size_t)r * S_ + jt * 64 + c8 * 8);
        }
        __syncthreads();

        // S strip (16x64) = Q strip @ K^T
        f32x4 s[4] = {};
#pragma unroll
        for (int kc = 0; kc < 2; ++kc)
#pragma unroll
            for (int ni = 0; ni < 4; ++ni) {
                bf16x8 kf = *(const bf16x8*)&Ks[ni * 16 + ln][kc * 32 + quad * 8];
                s[ni] = __builtin_amdgcn_mfma_f32_16x16x32_bf16(qf[kc], kf, s[ni], 0, 0, 0);
            }

        // scale + causal mask (diag tile only: col > row)
        const bool diag = (jt == qb);
        float sc[4][4];  // [ni][r]
#pragma unroll
        for (int ni = 0; ni < 4; ++ni)
#pragma unroll
            for (int r = 0; r < 4; ++r) {
                float v = s[ni][r] * scale;
                if (diag && (ni * 16 + ln) > (w * 16 + quad * 4 + r)) v = -1e30f;
                sc[ni][r] = v;
            }

        // online softmax per row (row fixed per (quad, r); cols across 16 lanes)
#pragma unroll
        for (int r = 0; r < 4; ++r) {
            float rmax = fmaxf(fmaxf(sc[0][r], sc[1][r]), fmaxf(sc[2][r], sc[3][r]));
#pragma unroll
            for (int off = 1; off < 16; off <<= 1)
                rmax = fmaxf(rmax, __shfl_xor(rmax, off, 16));
            float mnew  = fmaxf(m_r[r], rmax);
            float alpha = __expf(m_r[r] - mnew);
            float rs = 0.f;
#pragma unroll
            for (int ni = 0; ni < 4; ++ni) {
                float p = __expf(sc[ni][r] - mnew);
                sc[ni][r] = p;
                rs += p;
            }
#pragma unroll
            for (int off = 1; off < 16; off <<= 1)
                rs += __shfl_xor(rs, off, 16);
            l_r[r] = l_r[r] * alpha + rs;
            m_r[r] = mnew;
#pragma unroll
            for (int ni = 0; ni < 4; ++ni) o[ni][r] *= alpha;
            // P -> LDS row-major (per-wave region rows [16w,16w+16))
#pragma unroll
            for (int ni = 0; ni < 4; ++ni)
                Ps[w * 16 + quad * 4 + r][ni * 16 + ln] = f2bf(sc[ni][r]);
        }
        __syncthreads();   // P visible (and K reads done)

        // O strip += P @ V  (A=P via A-layout reads, B=Vt rows)
#pragma unroll
        for (int kc = 0; kc < 2; ++kc) {
            bf16x8 pa = *(const bf16x8*)&Ps[w * 16 + ln][kc * 32 + quad * 8];
#pragma unroll
            for (int ni = 0; ni < 4; ++ni) {
                bf16x8 vb = *(const bf16x8*)&Vts[ni * 16 + ln][kc * 32 + quad * 8];
                o[ni] = __builtin_amdgcn_mfma_f32_16x16x32_bf16(pa, vb, o[ni], 0, 0, 0);
            }
        }
    }

    // epilogue: attn2[b, s, h*64+p] bf16
#pragma unroll
    for (int ni = 0; ni < 4; ++ni)
#pragma unroll
        for (int r = 0; r < 4; ++r) {
            int gi = qb * 64 + w * 16 + quad * 4 + r;
            float val = o[ni][r] / l_r[r];
            attn2[((size_t)b * S_ + gi) * (H_ * P_) + h * P_ + ni * 16 + ln] = f2bf(val);
        }
}

// ---------------------------------------------------------------------------
// Stage 4: out(8192x768) = attn2 @ lifting, via liftT (Bt form). grid (64,12).
// fp32 output.
// ---------------------------------------------------------------------------
__global__ __launch_bounds__(256) void lift_mfma(
    const short* __restrict__ attn2,
    const short* __restrict__ liftT,
    float* __restrict__ outp)
{
    __shared__ short As[128][72];
    __shared__ short Bs[64][72];
    const int tid = threadIdx.x;
    const int w = tid >> 6, lane = tid & 63, quad = lane >> 4, ln = lane & 15;
    const int m0 = blockIdx.x * 128;
    const int n0 = blockIdx.y * 64;

    f32x4 acc[2][4] = {};
    mfma_gemm_128x64(attn2 + (size_t)m0 * E_, E_,
                     liftT + (size_t)n0 * E_, E_, E_, As, Bs, acc);

#pragma unroll
    for (int mi = 0; mi < 2; ++mi)
#pragma unroll
        for (int ni = 0; ni < 4; ++ni)
#pragma unroll
            for (int r = 0; r < 4; ++r) {
                int m = m0 + w * 32 + mi * 16 + quad * 4 + r;
                outp[(size_t)m * E_ + n0 + ni * 16 + ln] = acc[mi][ni][r];
            }
}

extern "C" void kernel_launch(void* const* d_in, const int* in_sizes, int n_in,
                              void* d_out, int out_size, void* d_ws, size_t ws_size,
                              hipStream_t stream) {
    (void)in_sizes; (void)n_in; (void)out_size; (void)ws_size;
    const float* x       = (const float*)d_in[0];
    const float* kproj   = (const float*)d_in[1];
    const float* vproj   = (const float*)d_in[2];
    const float* qheads  = (const float*)d_in[3];
    const float* lifting = (const float*)d_in[4];
    float* out = (float*)d_out;

    short* ws = (short*)d_ws;
    const size_t N_X   = (size_t)B_ * S_ * E_;          // 6,291,456
    const size_t N_QH  = (size_t)H_ * S_ * S_;          // 12,582,912
    const size_t N_W   = (size_t)H_ * P_ * E_;          //    589,824
    const size_t N_L   = (size_t)E_ * E_;               //    589,824
    const size_t N_KV  = (size_t)B_ * H_ * S_ * P_;     // 6,291,456

    short* xb    = ws;                 ws += N_X;
    short* qhb   = ws;                 ws += N_QH;
    short* kTw   = ws;                 ws += N_W;
    short* vTw   = ws;                 ws += N_W;
    short* liftT = ws;                 ws += N_L;
    short* kb    = ws;                 ws += N_KV;
    short* vTb   = ws;                 ws += N_KV;
    short* qvb   = ws;                 ws += N_KV;
    short* attn2 = ws;                 ws += N_KV;

    conv_bf16_kernel<<<(int)(N_X / 1024), 256, 0, stream>>>((const float4*)x, (ushort4*)xb);
    conv_bf16_kernel<<<(int)(N_QH / 1024), 256, 0, stream>>>((const float4*)qheads, (ushort4*)qhb);
    conv_T_kernel<<<dim3(E_ / 64, P_ / 64, H_), 256, 0, stream>>>(kproj, kTw, E_, P_);
    conv_T_kernel<<<dim3(E_ / 64, P_ / 64, H_), 256, 0, stream>>>(vproj, vTw, E_, P_);
    conv_T_kernel<<<dim3(E_ / 64, E_ / 64, 1), 256, 0, stream>>>(lifting, liftT, E_, E_);

    proj_kv_mfma<<<dim3((B_ * S_) / 128, H_, 2), 256, 0, stream>>>(xb, kTw, vTw, kb, vTb);
    qv_mfma<<<dim3(S_ / 128, B_ * H_), 256, 0, stream>>>(qhb, vTb, qvb);
    flash_mfma<<<dim3(S_ / 64, B_ * H_), 256, 0, stream>>>(kb, qvb, vTb, attn2);
    lift_mfma<<<dim3((B_ * S_) / 128, E_ / 64), 256, 0, stream>>>(attn2, liftT, out);
}